// Round 23
// baseline (400.139 us; speedup 1.0000x reference)
//
#include <hip/hip_runtime.h>

#define DH 128
#define NB 65536   // hi16 buckets
#define CDIV(a,b) (((a)+(b)-1)/(b))

// ---------------- utility ----------------
// both attn norms in one launch; per-norm arithmetic identical to before
__global__ void norm2_kernel(const float* __restrict__ a1, const float* __restrict__ a2,
                             float* __restrict__ nrm1, float* __restrict__ nrm2) {
  int t = threadIdx.x;
  if (t != 0 && t != 64) return;
  const float* a = (t == 0) ? a1 : a2;
  float* nrm = (t == 0) ? nrm1 : nrm2;
  float c[4][8];
  #pragma unroll
  for (int m = 0; m < 4; ++m)
    #pragma unroll
    for (int l = 0; l < 8; ++l) c[m][l] = 0.f;
  for (int i = 0; i < 128; i += 32) {
    #pragma unroll
    for (int m = 0; m < 4; ++m)
      #pragma unroll
      for (int l = 0; l < 8; ++l) {
        float x = a[i + m * 8 + l];
        c[m][l] = fmaf(x, x, c[m][l]);
      }
  }
  float s[8];
  #pragma unroll
  for (int l = 0; l < 8; ++l) s[l] = (c[0][l] + c[1][l]) + (c[2][l] + c[3][l]);
  float b0 = s[0] + s[4], b1 = s[1] + s[5], b2 = s[2] + s[6], b3 = s[3] + s[7];
  nrm[0] = sqrtf((b0 + b1) + (b2 + b3));
}

// ---------------- single-block exclusive scan over NB=65536 bins ----------------
// 1024 threads x 64 consecutive bins each: serial local sums -> LDS ladder over
// 1024 partials -> re-walk writing exclusive starts. Exact integer scan.
__global__ __launch_bounds__(1024) void scan64k(const int* __restrict__ hist,
                                                int* __restrict__ start) {
  __shared__ int part[1024];
  const int t = threadIdx.x;
  const int base = t * 64;
  int loc[64];
  int sum = 0;
  #pragma unroll
  for (int j = 0; j < 64; ++j) { loc[j] = hist[base + j]; sum += loc[j]; }
  part[t] = sum;
  __syncthreads();
  for (int off = 1; off < 1024; off <<= 1) {
    int v = (t >= off) ? part[t - off] : 0;
    __syncthreads();
    part[t] += v;
    __syncthreads();
  }
  int running = part[t] - sum;  // exclusive prefix of this thread's chunk
  #pragma unroll
  for (int j = 0; j < 64; ++j) { start[base + j] = running; running += loc[j]; }
}

// ---------------- dual exclusive scan: rowptr (from cnt) + prow (from padded cnt) ----
__global__ __launch_bounds__(256) void scanA2(const int* __restrict__ cnt,
                                              int* __restrict__ rowptr, int* __restrict__ prow,
                                              int2* __restrict__ bsum2, int m) {
  __shared__ int bufA[256], bufB[256];
  int i = blockIdx.x * 256 + threadIdx.x;
  int c = (i < m) ? cnt[i] : 0;
  int p = ((c + 7) >> 3) << 3;
  bufA[threadIdx.x] = c; bufB[threadIdx.x] = p;
  __syncthreads();
  for (int off = 1; off < 256; off <<= 1) {
    int tA = (threadIdx.x >= off) ? bufA[threadIdx.x - off] : 0;
    int tB = (threadIdx.x >= off) ? bufB[threadIdx.x - off] : 0;
    __syncthreads();
    bufA[threadIdx.x] += tA; bufB[threadIdx.x] += tB;
    __syncthreads();
  }
  if (i < m) { rowptr[i] = bufA[threadIdx.x] - c; prow[i] = bufB[threadIdx.x] - p; }
  if (threadIdx.x == 255) bsum2[blockIdx.x] = make_int2(bufA[255], bufB[255]);
}
__global__ __launch_bounds__(1024) void scanB2(int2* __restrict__ bsum2, int nblk) {
  __shared__ int bufA[1024], bufB[1024];
  int2 v = (threadIdx.x < nblk) ? bsum2[threadIdx.x] : make_int2(0, 0);
  bufA[threadIdx.x] = v.x; bufB[threadIdx.x] = v.y;
  __syncthreads();
  for (int off = 1; off < 1024; off <<= 1) {
    int tA = (threadIdx.x >= off) ? bufA[threadIdx.x - off] : 0;
    int tB = (threadIdx.x >= off) ? bufB[threadIdx.x - off] : 0;
    __syncthreads();
    bufA[threadIdx.x] += tA; bufB[threadIdx.x] += tB;
    __syncthreads();
  }
  if (threadIdx.x < nblk) bsum2[threadIdx.x] = make_int2(bufA[threadIdx.x] - v.x, bufB[threadIdx.x] - v.y);
}
// also writes rowptr[m] = Etot
__global__ __launch_bounds__(256) void scanC2(int* __restrict__ rowptr, int* __restrict__ prow,
                                              const int2* __restrict__ bsum2, int m, int Etot) {
  int i = blockIdx.x * 256 + threadIdx.x;
  if (i < m) { int2 b = bsum2[blockIdx.x]; rowptr[i] += b.x; prow[i] += b.y; }
  if (blockIdx.x == 0 && threadIdx.x == 0) rowptr[m] = Etot;
}

// ---------------- CSR build (deterministic) ----------------
__global__ void count_kernel(const int* __restrict__ dst, int* __restrict__ cnt, int E) {
  int e = blockIdx.x * 256 + threadIdx.x;
  if (e < E) atomicAdd(&cnt[dst[e]], 1);
}
__global__ void scatter_kernel(const int* __restrict__ dst, const int* __restrict__ rowptr,
                               int* __restrict__ fill, int* __restrict__ eids, int E) {
  int e = blockIdx.x * 256 + threadIdx.x;
  if (e >= E) return;
  int d = dst[e];
  int slot = rowptr[d] + atomicAdd(&fill[d], 1);
  eids[slot] = e;
}
// fused: per-node insertion sort (ascending edge id) + padded-slot map emit
__global__ void sortmap_kernel(const int* __restrict__ rowptr, const int* __restrict__ prow,
                               int* __restrict__ eids, int* __restrict__ map, int n) {
  int v = blockIdx.x * 256 + threadIdx.x;
  if (v >= n) return;
  int lo = rowptr[v], hi = rowptr[v + 1];
  for (int a = lo + 1; a < hi; ++a) {
    int key = eids[a];
    int b = a - 1;
    while (b >= lo && eids[b] > key) { eids[b + 1] = eids[b]; --b; }
    eids[b + 1] = key;
  }
  int p0 = prow[v];
  for (int j = 0; j < hi - lo; ++j) map[lo + j] = p0 + j;
}
__global__ void count2_kernel(const int* __restrict__ src, const int* __restrict__ dst,
                              const int* __restrict__ rank, int kk, int* __restrict__ cnt2, int E) {
  int e = blockIdx.x * 256 + threadIdx.x;
  if (e >= E) return;
  int rs = rank[src[e]], rd = rank[dst[e]];
  if (rs < kk && rd < kk) atomicAdd(&cnt2[rd], 1);
}

// per-padded-slot operands: {src_row, nm_bits}, nm = dinv[src]*dinv[dst].
__global__ void csr_prep(const int* __restrict__ eids, const int* __restrict__ src,
                         const int* __restrict__ dst, const int* __restrict__ map,
                         const int* __restrict__ rank, int kk,
                         const int* __restrict__ cntv,
                         int2* __restrict__ pk, int E) {
  int idx = blockIdx.x * 256 + threadIdx.x;
  if (idx >= E) return;
  int e = eids[idx];
  int s = src[e], d = dst[e];
  int pos = map[idx];
  if (rank) {
    int rs = rank[s], rd = rank[d];
    if (rs < kk && rd < kk) {
      float ds = 1.0f / sqrtf((float)(cntv[rs] + 1));
      float dd = 1.0f / sqrtf((float)(cntv[rd] + 1));
      pk[pos] = make_int2(rs, __float_as_int(ds * dd));
    } else {
      pk[pos] = make_int2(0, 0);
    }
  } else {
    float ds = 1.0f / sqrtf((float)(cntv[s] + 1));
    float dd = 1.0f / sqrtf((float)(cntv[d] + 1));
    pk[pos] = make_int2(s, __float_as_int(ds * dd));
  }
}

// ---------------- GEMM (OpenBLAS rounding: per-(i,j) acc, k ascending, FMA) ----
// X tile in LDS; W per-kc slice double-buffered in LDS. Bit-exact chain.
__global__ __launch_bounds__(128) void gemm_128(const float* __restrict__ X,
                                                const float* __restrict__ W,
                                                float* __restrict__ C, int n) {
  __shared__ float Xs[32][132];
  __shared__ float Ws[2][512];
  const int row0 = blockIdx.x * 32;

  for (int j = threadIdx.x; j < 1024; j += 128) {
    int r = j >> 5;
    int c4 = j & 31;
    float4 v = (row0 + r < n) ? *(const float4*)&X[((size_t)(row0 + r)) * DH + c4 * 4]
                              : make_float4(0.f, 0.f, 0.f, 0.f);
    *(float4*)&Xs[r][c4 * 4] = v;
  }
  {
    float4 w0 = *(const float4*)&W[threadIdx.x * 4];
    *(float4*)&Ws[0][threadIdx.x * 4] = w0;
  }
  __syncthreads();

  const int c0 = (threadIdx.x & 15) << 3;
  const int r0 = (threadIdx.x >> 4) << 2;

  int gr[4];
  bool inb[4];
  #pragma unroll
  for (int i = 0; i < 4; ++i) { gr[i] = row0 + r0 + i; inb[i] = gr[i] < n; }

  float acc[4][8];
  #pragma unroll
  for (int i = 0; i < 4; ++i)
    #pragma unroll
    for (int j = 0; j < 8; ++j) acc[i][j] = 0.f;

  for (int kc = 0; kc < 32; ++kc) {
    const int cur = kc & 1;
    float4 wpre;
    if (kc < 31)
      wpre = *(const float4*)&W[(kc + 1) * 512 + threadIdx.x * 4];

    float4 xr[4];
    #pragma unroll
    for (int i = 0; i < 4; ++i)
      xr[i] = *(const float4*)&Xs[r0 + i][kc * 4];

    #pragma unroll
    for (int kk = 0; kk < 4; ++kk) {
      float4 wa = *(const float4*)&Ws[cur][kk * 128 + c0];
      float4 wb = *(const float4*)&Ws[cur][kk * 128 + c0 + 4];
      float wv[8] = {wa.x, wa.y, wa.z, wa.w, wb.x, wb.y, wb.z, wb.w};
      #pragma unroll
      for (int i = 0; i < 4; ++i) {
        float xk = ((const float*)&xr[i])[kk];
        #pragma unroll
        for (int j = 0; j < 8; ++j)
          acc[i][j] = fmaf(xk, wv[j], acc[i][j]);
      }
    }
    if (kc < 31)
      *(float4*)&Ws[cur ^ 1][threadIdx.x * 4] = wpre;
    __syncthreads();
  }
  #pragma unroll
  for (int i = 0; i < 4; ++i) {
    if (inb[i]) {
      *(float4*)&C[(size_t)gr[i] * DH + c0] =
          make_float4(acc[i][0], acc[i][1], acc[i][2], acc[i][3]);
      *(float4*)&C[(size_t)gr[i] * DH + c0 + 4] =
          make_float4(acc[i][4], acc[i][5], acc[i][6], acc[i][7]);
    }
  }
}

// ---------------- fused GCN conv + score ----------------
__global__ __launch_bounds__(256) void conv_kernel(
    const float* __restrict__ h, const float* __restrict__ bias,
    const int* __restrict__ prow, const int* __restrict__ cnt_orig,
    const int2* __restrict__ pk,
    const int* __restrict__ sel,      // level2: new->orig (null for level1)
    const int* __restrict__ cnt_dv,   // degree source for dv (cnt or cnt2)
    const float* __restrict__ attn, const float* __restrict__ nrm,
    float* __restrict__ out, float* __restrict__ score,
    unsigned* __restrict__ s32, int* __restrict__ hist, int nodes) {
  #pragma clang fp contract(off)
  __shared__ float at[128];
  __shared__ float hrow[4][128];
  __shared__ float chn[4][16];
  if (threadIdx.x < 32)
    *(float4*)&at[threadIdx.x * 4] = *(const float4*)&attn[threadIdx.x * 4];

  int nl = threadIdx.x >> 6;
  int node = blockIdx.x * 4 + nl;
  int d0 = (threadIdx.x & 63) << 1;
  if (node < nodes) {
    int v_orig = sel ? sel[node] : node;
    float dv = 1.0f / sqrtf((float)(cnt_dv[node] + 1));
    float acc0 = 0.f, acc1 = 0.f;
    int base = prow[v_orig];
    int chunks = (cnt_orig[v_orig] + 7) >> 3;
    for (int cc = 0; cc < chunks; ++cc) {
      int2 p[8];
      float2 hv[8];
      #pragma unroll
      for (int q = 0; q < 8; ++q) p[q] = pk[base + q];
      #pragma unroll
      for (int q = 0; q < 8; ++q) hv[q] = *(const float2*)&h[(size_t)p[q].x * DH + d0];
      #pragma unroll
      for (int q = 0; q < 8; ++q) {
        float nm = __int_as_float(p[q].y);
        float t0 = hv[q].x * nm;
        float t1 = hv[q].y * nm;
        acc0 = acc0 + t0;
        acc1 = acc1 + t1;
      }
      base += 8;
    }
    float dvv = dv * dv;
    float2 hs = *(const float2*)&h[(size_t)node * DH + d0];
    float s0 = hs.x * dvv;
    float s1 = hs.y * dvv;
    float r0 = (acc0 + s0) + bias[d0];
    float r1 = (acc1 + s1) + bias[d0 + 1];
    float2 o;
    o.x = r0 > 0.f ? r0 : 0.f;
    o.y = r1 > 0.f ? r1 : 0.f;
    *(float2*)&out[(size_t)node * DH + d0] = o;
    hrow[nl][d0] = o.x;
    hrow[nl][d0 + 1] = o.y;
  }
  __syncthreads();
  if (threadIdx.x < 64) {
    int nl2 = threadIdx.x >> 4;
    int j = threadIdx.x & 15;
    if (blockIdx.x * 4 + nl2 < nodes) {
      float c = 0.f;
      #pragma unroll
      for (int t = 0; t < 8; ++t)
        c = fmaf(hrow[nl2][t * 16 + j], at[t * 16 + j], c);
      chn[nl2][j] = c;
    }
  }
  __syncthreads();
  if (threadIdx.x < 4) {
    int node2 = blockIdx.x * 4 + threadIdx.x;
    if (node2 < nodes) {
      const float* c = chn[threadIdx.x];
      float s8[8];
      #pragma unroll
      for (int l = 0; l < 8; ++l) s8[l] = c[l] + c[l + 8];
      float s4[4];
      #pragma unroll
      for (int l = 0; l < 4; ++l) s4[l] = s8[l] + s8[l + 4];
      float dot = (s4[0] + s4[1]) + (s4[2] + s4[3]);
      float q = dot / nrm[0];
      float sc = (float)tanh((double)q);
      score[node2] = sc;
      unsigned u = __float_as_uint(sc);
      unsigned sb = (u & 0x80000000u) ? ~u : (u | 0x80000000u);
      s32[node2] = sb;
      atomicAdd(&hist[sb >> 16], 1);
    }
  }
}

// ---------------- bucketed exact ranking ----------------
__global__ void scatter32_kernel(const unsigned* __restrict__ s32, const int* __restrict__ start,
                                 int* __restrict__ fill2, unsigned long long* __restrict__ mem64,
                                 int n) {
  int i = blockIdx.x * 256 + threadIdx.x;
  if (i >= n) return;
  unsigned si = s32[i];
  int b = si >> 16;
  int pos = start[b] + atomicAdd(&fill2[b], 1);
  mem64[pos] = ((unsigned long long)si << 32) | (unsigned)(~i);
}
__global__ void rank_bucket_kernel(const unsigned* __restrict__ s32, const int* __restrict__ start,
                                   const int* __restrict__ hist,
                                   const unsigned long long* __restrict__ mem64,
                                   int n, int* __restrict__ rank) {
  int i = blockIdx.x * 256 + threadIdx.x;
  if (i >= n) return;
  unsigned si = s32[i];
  int b = si >> 16;
  int lo = start[b], m = hist[b];
  unsigned long long ki = ((unsigned long long)si << 32) | (unsigned)(~i);
  int cnt = n - lo - m;
  for (int t = 0; t < m; ++t) cnt += (mem64[lo + t] > ki) ? 1 : 0;
  rank[i] = cnt;
}

// fused select + gather
__global__ __launch_bounds__(256) void select_gather(const float* __restrict__ h,
    const float* __restrict__ score, const int* __restrict__ rank,
    int k, int* __restrict__ sel, float* __restrict__ outp, int n) {
  int lane = threadIdx.x & 31;
  int i = blockIdx.x * 8 + (threadIdx.x >> 5);
  if (i >= n) return;
  int r = rank[i];
  if (r >= k) return;
  float v = score[i];
  if (lane == 0) sel[r] = i;
  float4 x = *(const float4*)&h[(size_t)i * DH + (lane << 2)];
  *(float4*)&outp[(size_t)r * DH + (lane << 2)] =
      make_float4(x.x * v, x.y * v, x.z * v, x.w * v);
}

// ---------------- host ----------------
extern "C" void kernel_launch(void* const* d_in, const int* in_sizes, int n_in,
                              void* d_out, int out_size, void* d_ws, size_t ws_size,
                              hipStream_t stream) {
  const float* X  = (const float*)d_in[0];
  const int*   ei = (const int*)d_in[1];
  const float* W1 = (const float*)d_in[3];
  const float* b1 = (const float*)d_in[4];
  const float* a1 = (const float*)d_in[5];
  const float* W2 = (const float*)d_in[6];
  const float* b2 = (const float*)d_in[7];
  const float* a2 = (const float*)d_in[8];
  float* out = (float*)d_out;

  const int n  = in_sizes[0] / DH;
  const int E  = in_sizes[1] / 2;
  const int k1 = (4 * n + 4) / 5;
  const int k2 = (4 * k1 + 4) / 5;
  const int Pmax = E + 8 * n;
  const int* src = ei;
  const int* dst = ei + E;

  char* w = (char*)d_ws;
  size_t off = 0;
  auto alloc = [&](size_t bytes) { void* p = w + off; off += (bytes + 255) & ~(size_t)255; return p; };
  float* hA     = (float*)alloc((size_t)n * DH * 4);
  float* hB     = (float*)alloc((size_t)n * DH * 4);
  float* xp     = (float*)alloc((size_t)k1 * DH * 4);
  int*   cnt    = (int*)  alloc((size_t)n * 4);
  int*   fill   = (int*)  alloc((size_t)n * 4);   // adjacent to cnt: one memset
  int*   rowptr = (int*)  alloc((size_t)(n + 1) * 4);
  int*   eids   = (int*)  alloc((size_t)E * 4);
  int*   prow   = (int*)  alloc((size_t)n * 4);
  int*   map    = (int*)  alloc((size_t)E * 4);
  int2*  pk     = (int2*) alloc((size_t)Pmax * 8);
  int*   cnt2   = (int*)  alloc((size_t)k1 * 4);
  float* score1 = (float*)alloc((size_t)n * 4);
  float* score2 = (float*)alloc((size_t)k1 * 4);
  int*   rank1  = (int*)  alloc((size_t)n * 4);
  int*   rank2  = (int*)  alloc((size_t)k1 * 4);
  unsigned* s32 = (unsigned*)alloc((size_t)n * 4);
  int*   hist   = (int*)  alloc((size_t)NB * 4);   // hist+fill2 adjacent: one memset
  int*   fill2  = (int*)  alloc((size_t)NB * 4);
  int*   start  = (int*)  alloc((size_t)NB * 4);
  unsigned long long* mem64 = (unsigned long long*)alloc((size_t)n * 8);
  int2*  bsum2  = (int2*) alloc((size_t)1024 * 8);
  int*   sel1   = (int*)  alloc((size_t)k1 * 4);
  int*   sel2   = (int*)  alloc((size_t)k2 * 4);
  float* nrm1   = (float*)alloc(256);
  float* nrm2   = (float*)alloc(256);

  auto rank_pass = [&](const unsigned* s32p, int* rank, int nL) {
    scan64k<<<1, 1024, 0, stream>>>(hist, start);
    scatter32_kernel<<<CDIV(nL, 256), 256, 0, stream>>>(s32p, start, fill2, mem64, nL);
    rank_bucket_kernel<<<CDIV(nL, 256), 256, 0, stream>>>(s32p, start, hist, mem64, nL, rank);
  };

  // ---- CSR build ----
  hipMemsetAsync(cnt, 0, (size_t)((char*)fill - (char*)cnt) + (size_t)n * 4, stream);
  norm2_kernel<<<1, 128, 0, stream>>>(a1, a2, nrm1, nrm2);
  count_kernel<<<CDIV(E, 256), 256, 0, stream>>>(dst, cnt, E);
  {
    int nblk = CDIV(n, 256);
    scanA2<<<nblk, 256, 0, stream>>>(cnt, rowptr, prow, bsum2, n);
    scanB2<<<1, 1024, 0, stream>>>(bsum2, nblk);
    scanC2<<<nblk, 256, 0, stream>>>(rowptr, prow, bsum2, n, E);
  }
  scatter_kernel<<<CDIV(E, 256), 256, 0, stream>>>(dst, rowptr, fill, eids, E);
  sortmap_kernel<<<CDIV(n, 256), 256, 0, stream>>>(rowptr, prow, eids, map, n);
  hipMemsetAsync(pk, 0, (size_t)Pmax * 8, stream);

  // ---- level 1 ----
  gemm_128<<<CDIV(n, 32), 128, 0, stream>>>(X, W1, hA, n);
  csr_prep<<<CDIV(E, 256), 256, 0, stream>>>(eids, src, dst, map, nullptr, 0, cnt, pk, E);
  hipMemsetAsync(hist, 0, (size_t)NB * 8, stream);  // hist + fill2 (adjacent)
  conv_kernel<<<CDIV(n, 4), 256, 0, stream>>>(hA, b1, prow, cnt, pk, nullptr, cnt,
                                              a1, nrm1, hB, score1, s32, hist, n);
  rank_pass(s32, rank1, n);
  select_gather<<<CDIV(n, 8), 256, 0, stream>>>(hB, score1, rank1, k1, sel1, xp, n);

  // ---- level 2 ----
  gemm_128<<<CDIV(k1, 32), 128, 0, stream>>>(xp, W2, hA, k1);
  hipMemsetAsync(cnt2, 0, (size_t)k1 * 4, stream);
  count2_kernel<<<CDIV(E, 256), 256, 0, stream>>>(src, dst, rank1, k1, cnt2, E);
  csr_prep<<<CDIV(E, 256), 256, 0, stream>>>(eids, src, dst, map, rank1, k1, cnt2, pk, E);
  hipMemsetAsync(hist, 0, (size_t)NB * 8, stream);  // hist + fill2
  conv_kernel<<<CDIV(k1, 4), 256, 0, stream>>>(hA, b2, prow, cnt, pk, sel1, cnt2,
                                               a2, nrm2, hB, score2, s32, hist, k1);
  rank_pass(s32, rank2, k1);
  select_gather<<<CDIV(k1, 8), 256, 0, stream>>>(hB, score2, rank2, k2, sel2, out, k1);
}

// Round 24
// 378.079 us; speedup vs baseline: 1.0583x; 1.0583x over previous
//
#include <hip/hip_runtime.h>

#define DH 128
#define NB 65536   // hi16 buckets
#define CDIV(a,b) (((a)+(b)-1)/(b))

// ---------------- utility ----------------
// both attn norms in one launch; per-norm arithmetic identical to before
__global__ void norm2_kernel(const float* __restrict__ a1, const float* __restrict__ a2,
                             float* __restrict__ nrm1, float* __restrict__ nrm2) {
  int t = threadIdx.x;
  if (t != 0 && t != 64) return;
  const float* a = (t == 0) ? a1 : a2;
  float* nrm = (t == 0) ? nrm1 : nrm2;
  float c[4][8];
  #pragma unroll
  for (int m = 0; m < 4; ++m)
    #pragma unroll
    for (int l = 0; l < 8; ++l) c[m][l] = 0.f;
  for (int i = 0; i < 128; i += 32) {
    #pragma unroll
    for (int m = 0; m < 4; ++m)
      #pragma unroll
      for (int l = 0; l < 8; ++l) {
        float x = a[i + m * 8 + l];
        c[m][l] = fmaf(x, x, c[m][l]);
      }
  }
  float s[8];
  #pragma unroll
  for (int l = 0; l < 8; ++l) s[l] = (c[0][l] + c[1][l]) + (c[2][l] + c[3][l]);
  float b0 = s[0] + s[4], b1 = s[1] + s[5], b2 = s[2] + s[6], b3 = s[3] + s[7];
  nrm[0] = sqrtf((b0 + b1) + (b2 + b3));
}

// ---------------- generic 3-kernel exclusive scan (int) ----------------
__global__ __launch_bounds__(256) void scanA(const int* __restrict__ in, int* __restrict__ out,
                                             int* __restrict__ bsum, int m) {
  __shared__ int buf[256];
  int i = blockIdx.x * 256 + threadIdx.x;
  int v = (i < m) ? in[i] : 0;
  buf[threadIdx.x] = v;
  __syncthreads();
  for (int off = 1; off < 256; off <<= 1) {
    int t = (threadIdx.x >= off) ? buf[threadIdx.x - off] : 0;
    __syncthreads();
    buf[threadIdx.x] += t;
    __syncthreads();
  }
  if (i < m) out[i] = buf[threadIdx.x] - v;  // exclusive
  if (threadIdx.x == 255) bsum[blockIdx.x] = buf[255];
}
__global__ __launch_bounds__(1024) void scanB(int* __restrict__ bsum, int nblk) {
  __shared__ int buf[1024];
  int v = (threadIdx.x < nblk) ? bsum[threadIdx.x] : 0;
  buf[threadIdx.x] = v;
  __syncthreads();
  for (int off = 1; off < 1024; off <<= 1) {
    int t = (threadIdx.x >= off) ? buf[threadIdx.x - off] : 0;
    __syncthreads();
    buf[threadIdx.x] += t;
    __syncthreads();
  }
  if (threadIdx.x < nblk) bsum[threadIdx.x] = buf[threadIdx.x] - v;
}
__global__ __launch_bounds__(256) void scanC(int* __restrict__ out, const int* __restrict__ bsum, int m) {
  int i = blockIdx.x * 256 + threadIdx.x;
  if (i < m) out[i] += bsum[blockIdx.x];
}

// ---------------- dual exclusive scan: rowptr (from cnt) + prow (from padded cnt) ----
__global__ __launch_bounds__(256) void scanA2(const int* __restrict__ cnt,
                                              int* __restrict__ rowptr, int* __restrict__ prow,
                                              int2* __restrict__ bsum2, int m) {
  __shared__ int bufA[256], bufB[256];
  int i = blockIdx.x * 256 + threadIdx.x;
  int c = (i < m) ? cnt[i] : 0;
  int p = ((c + 7) >> 3) << 3;
  bufA[threadIdx.x] = c; bufB[threadIdx.x] = p;
  __syncthreads();
  for (int off = 1; off < 256; off <<= 1) {
    int tA = (threadIdx.x >= off) ? bufA[threadIdx.x - off] : 0;
    int tB = (threadIdx.x >= off) ? bufB[threadIdx.x - off] : 0;
    __syncthreads();
    bufA[threadIdx.x] += tA; bufB[threadIdx.x] += tB;
    __syncthreads();
  }
  if (i < m) { rowptr[i] = bufA[threadIdx.x] - c; prow[i] = bufB[threadIdx.x] - p; }
  if (threadIdx.x == 255) bsum2[blockIdx.x] = make_int2(bufA[255], bufB[255]);
}
__global__ __launch_bounds__(1024) void scanB2(int2* __restrict__ bsum2, int nblk) {
  __shared__ int bufA[1024], bufB[1024];
  int2 v = (threadIdx.x < nblk) ? bsum2[threadIdx.x] : make_int2(0, 0);
  bufA[threadIdx.x] = v.x; bufB[threadIdx.x] = v.y;
  __syncthreads();
  for (int off = 1; off < 1024; off <<= 1) {
    int tA = (threadIdx.x >= off) ? bufA[threadIdx.x - off] : 0;
    int tB = (threadIdx.x >= off) ? bufB[threadIdx.x - off] : 0;
    __syncthreads();
    bufA[threadIdx.x] += tA; bufB[threadIdx.x] += tB;
    __syncthreads();
  }
  if (threadIdx.x < nblk) bsum2[threadIdx.x] = make_int2(bufA[threadIdx.x] - v.x, bufB[threadIdx.x] - v.y);
}
// also writes rowptr[m] = Etot
__global__ __launch_bounds__(256) void scanC2(int* __restrict__ rowptr, int* __restrict__ prow,
                                              const int2* __restrict__ bsum2, int m, int Etot) {
  int i = blockIdx.x * 256 + threadIdx.x;
  if (i < m) { int2 b = bsum2[blockIdx.x]; rowptr[i] += b.x; prow[i] += b.y; }
  if (blockIdx.x == 0 && threadIdx.x == 0) rowptr[m] = Etot;
}

// ---------------- CSR build (deterministic) ----------------
__global__ void count_kernel(const int* __restrict__ dst, int* __restrict__ cnt, int E) {
  int e = blockIdx.x * 256 + threadIdx.x;
  if (e < E) atomicAdd(&cnt[dst[e]], 1);
}
__global__ void scatter_kernel(const int* __restrict__ dst, const int* __restrict__ rowptr,
                               int* __restrict__ fill, int* __restrict__ eids, int E) {
  int e = blockIdx.x * 256 + threadIdx.x;
  if (e >= E) return;
  int d = dst[e];
  int slot = rowptr[d] + atomicAdd(&fill[d], 1);
  eids[slot] = e;
}
// fused: per-node insertion sort (ascending edge id) + padded-slot map emit
__global__ void sortmap_kernel(const int* __restrict__ rowptr, const int* __restrict__ prow,
                               int* __restrict__ eids, int* __restrict__ map, int n) {
  int v = blockIdx.x * 256 + threadIdx.x;
  if (v >= n) return;
  int lo = rowptr[v], hi = rowptr[v + 1];
  for (int a = lo + 1; a < hi; ++a) {
    int key = eids[a];
    int b = a - 1;
    while (b >= lo && eids[b] > key) { eids[b + 1] = eids[b]; --b; }
    eids[b + 1] = key;
  }
  int p0 = prow[v];
  for (int j = 0; j < hi - lo; ++j) map[lo + j] = p0 + j;
}
__global__ void count2_kernel(const int* __restrict__ src, const int* __restrict__ dst,
                              const int* __restrict__ rank, int kk, int* __restrict__ cnt2, int E) {
  int e = blockIdx.x * 256 + threadIdx.x;
  if (e >= E) return;
  int rs = rank[src[e]], rd = rank[dst[e]];
  if (rs < kk && rd < kk) atomicAdd(&cnt2[rd], 1);
}

// per-padded-slot operands: {src_row, nm_bits}, nm = dinv[src]*dinv[dst].
__global__ void csr_prep(const int* __restrict__ eids, const int* __restrict__ src,
                         const int* __restrict__ dst, const int* __restrict__ map,
                         const int* __restrict__ rank, int kk,
                         const int* __restrict__ cntv,
                         int2* __restrict__ pk, int E) {
  int idx = blockIdx.x * 256 + threadIdx.x;
  if (idx >= E) return;
  int e = eids[idx];
  int s = src[e], d = dst[e];
  int pos = map[idx];
  if (rank) {
    int rs = rank[s], rd = rank[d];
    if (rs < kk && rd < kk) {
      float ds = 1.0f / sqrtf((float)(cntv[rs] + 1));
      float dd = 1.0f / sqrtf((float)(cntv[rd] + 1));
      pk[pos] = make_int2(rs, __float_as_int(ds * dd));
    } else {
      pk[pos] = make_int2(0, 0);
    }
  } else {
    float ds = 1.0f / sqrtf((float)(cntv[s] + 1));
    float dd = 1.0f / sqrtf((float)(cntv[d] + 1));
    pk[pos] = make_int2(s, __float_as_int(ds * dd));
  }
}

// ---------------- GEMM (OpenBLAS rounding: per-(i,j) acc, k ascending, FMA) ----
// X tile in LDS; W per-kc slice double-buffered in LDS. Bit-exact chain.
__global__ __launch_bounds__(128) void gemm_128(const float* __restrict__ X,
                                                const float* __restrict__ W,
                                                float* __restrict__ C, int n) {
  __shared__ float Xs[32][132];
  __shared__ float Ws[2][512];
  const int row0 = blockIdx.x * 32;

  for (int j = threadIdx.x; j < 1024; j += 128) {
    int r = j >> 5;
    int c4 = j & 31;
    float4 v = (row0 + r < n) ? *(const float4*)&X[((size_t)(row0 + r)) * DH + c4 * 4]
                              : make_float4(0.f, 0.f, 0.f, 0.f);
    *(float4*)&Xs[r][c4 * 4] = v;
  }
  {
    float4 w0 = *(const float4*)&W[threadIdx.x * 4];
    *(float4*)&Ws[0][threadIdx.x * 4] = w0;
  }
  __syncthreads();

  const int c0 = (threadIdx.x & 15) << 3;
  const int r0 = (threadIdx.x >> 4) << 2;

  int gr[4];
  bool inb[4];
  #pragma unroll
  for (int i = 0; i < 4; ++i) { gr[i] = row0 + r0 + i; inb[i] = gr[i] < n; }

  float acc[4][8];
  #pragma unroll
  for (int i = 0; i < 4; ++i)
    #pragma unroll
    for (int j = 0; j < 8; ++j) acc[i][j] = 0.f;

  for (int kc = 0; kc < 32; ++kc) {
    const int cur = kc & 1;
    float4 wpre;
    if (kc < 31)
      wpre = *(const float4*)&W[(kc + 1) * 512 + threadIdx.x * 4];

    float4 xr[4];
    #pragma unroll
    for (int i = 0; i < 4; ++i)
      xr[i] = *(const float4*)&Xs[r0 + i][kc * 4];

    #pragma unroll
    for (int kk = 0; kk < 4; ++kk) {
      float4 wa = *(const float4*)&Ws[cur][kk * 128 + c0];
      float4 wb = *(const float4*)&Ws[cur][kk * 128 + c0 + 4];
      float wv[8] = {wa.x, wa.y, wa.z, wa.w, wb.x, wb.y, wb.z, wb.w};
      #pragma unroll
      for (int i = 0; i < 4; ++i) {
        float xk = ((const float*)&xr[i])[kk];
        #pragma unroll
        for (int j = 0; j < 8; ++j)
          acc[i][j] = fmaf(xk, wv[j], acc[i][j]);
      }
    }
    if (kc < 31)
      *(float4*)&Ws[cur ^ 1][threadIdx.x * 4] = wpre;
    __syncthreads();
  }
  #pragma unroll
  for (int i = 0; i < 4; ++i) {
    if (inb[i]) {
      *(float4*)&C[(size_t)gr[i] * DH + c0] =
          make_float4(acc[i][0], acc[i][1], acc[i][2], acc[i][3]);
      *(float4*)&C[(size_t)gr[i] * DH + c0 + 4] =
          make_float4(acc[i][4], acc[i][5], acc[i][6], acc[i][7]);
    }
  }
}

// ---------------- fused GCN conv + score ----------------
__global__ __launch_bounds__(256) void conv_kernel(
    const float* __restrict__ h, const float* __restrict__ bias,
    const int* __restrict__ prow, const int* __restrict__ cnt_orig,
    const int2* __restrict__ pk,
    const int* __restrict__ sel,      // level2: new->orig (null for level1)
    const int* __restrict__ cnt_dv,   // degree source for dv (cnt or cnt2)
    const float* __restrict__ attn, const float* __restrict__ nrm,
    float* __restrict__ out, float* __restrict__ score,
    unsigned* __restrict__ s32, int* __restrict__ hist, int nodes) {
  #pragma clang fp contract(off)
  __shared__ float at[128];
  __shared__ float hrow[4][128];
  __shared__ float chn[4][16];
  if (threadIdx.x < 32)
    *(float4*)&at[threadIdx.x * 4] = *(const float4*)&attn[threadIdx.x * 4];

  int nl = threadIdx.x >> 6;
  int node = blockIdx.x * 4 + nl;
  int d0 = (threadIdx.x & 63) << 1;
  if (node < nodes) {
    int v_orig = sel ? sel[node] : node;
    float dv = 1.0f / sqrtf((float)(cnt_dv[node] + 1));
    float acc0 = 0.f, acc1 = 0.f;
    int base = prow[v_orig];
    int chunks = (cnt_orig[v_orig] + 7) >> 3;
    for (int cc = 0; cc < chunks; ++cc) {
      int2 p[8];
      float2 hv[8];
      #pragma unroll
      for (int q = 0; q < 8; ++q) p[q] = pk[base + q];
      #pragma unroll
      for (int q = 0; q < 8; ++q) hv[q] = *(const float2*)&h[(size_t)p[q].x * DH + d0];
      #pragma unroll
      for (int q = 0; q < 8; ++q) {
        float nm = __int_as_float(p[q].y);
        float t0 = hv[q].x * nm;
        float t1 = hv[q].y * nm;
        acc0 = acc0 + t0;
        acc1 = acc1 + t1;
      }
      base += 8;
    }
    float dvv = dv * dv;
    float2 hs = *(const float2*)&h[(size_t)node * DH + d0];
    float s0 = hs.x * dvv;
    float s1 = hs.y * dvv;
    float r0 = (acc0 + s0) + bias[d0];
    float r1 = (acc1 + s1) + bias[d0 + 1];
    float2 o;
    o.x = r0 > 0.f ? r0 : 0.f;
    o.y = r1 > 0.f ? r1 : 0.f;
    *(float2*)&out[(size_t)node * DH + d0] = o;
    hrow[nl][d0] = o.x;
    hrow[nl][d0 + 1] = o.y;
  }
  __syncthreads();
  if (threadIdx.x < 64) {
    int nl2 = threadIdx.x >> 4;
    int j = threadIdx.x & 15;
    if (blockIdx.x * 4 + nl2 < nodes) {
      float c = 0.f;
      #pragma unroll
      for (int t = 0; t < 8; ++t)
        c = fmaf(hrow[nl2][t * 16 + j], at[t * 16 + j], c);
      chn[nl2][j] = c;
    }
  }
  __syncthreads();
  if (threadIdx.x < 4) {
    int node2 = blockIdx.x * 4 + threadIdx.x;
    if (node2 < nodes) {
      const float* c = chn[threadIdx.x];
      float s8[8];
      #pragma unroll
      for (int l = 0; l < 8; ++l) s8[l] = c[l] + c[l + 8];
      float s4[4];
      #pragma unroll
      for (int l = 0; l < 4; ++l) s4[l] = s8[l] + s8[l + 4];
      float dot = (s4[0] + s4[1]) + (s4[2] + s4[3]);
      float q = dot / nrm[0];
      float sc = (float)tanh((double)q);
      score[node2] = sc;
      unsigned u = __float_as_uint(sc);
      unsigned sb = (u & 0x80000000u) ? ~u : (u | 0x80000000u);
      s32[node2] = sb;
      atomicAdd(&hist[sb >> 16], 1);
    }
  }
}

// ---------------- bucketed exact ranking ----------------
__global__ void scatter32_kernel(const unsigned* __restrict__ s32, const int* __restrict__ start,
                                 int* __restrict__ fill2, unsigned long long* __restrict__ mem64,
                                 int n) {
  int i = blockIdx.x * 256 + threadIdx.x;
  if (i >= n) return;
  unsigned si = s32[i];
  int b = si >> 16;
  int pos = start[b] + atomicAdd(&fill2[b], 1);
  mem64[pos] = ((unsigned long long)si << 32) | (unsigned)(~i);
}
__global__ void rank_bucket_kernel(const unsigned* __restrict__ s32, const int* __restrict__ start,
                                   const int* __restrict__ hist,
                                   const unsigned long long* __restrict__ mem64,
                                   int n, int* __restrict__ rank) {
  int i = blockIdx.x * 256 + threadIdx.x;
  if (i >= n) return;
  unsigned si = s32[i];
  int b = si >> 16;
  int lo = start[b], m = hist[b];
  unsigned long long ki = ((unsigned long long)si << 32) | (unsigned)(~i);
  int cnt = n - lo - m;
  for (int t = 0; t < m; ++t) cnt += (mem64[lo + t] > ki) ? 1 : 0;
  rank[i] = cnt;
}

// fused select + gather
__global__ __launch_bounds__(256) void select_gather(const float* __restrict__ h,
    const float* __restrict__ score, const int* __restrict__ rank,
    int k, int* __restrict__ sel, float* __restrict__ outp, int n) {
  int lane = threadIdx.x & 31;
  int i = blockIdx.x * 8 + (threadIdx.x >> 5);
  if (i >= n) return;
  int r = rank[i];
  if (r >= k) return;
  float v = score[i];
  if (lane == 0) sel[r] = i;
  float4 x = *(const float4*)&h[(size_t)i * DH + (lane << 2)];
  *(float4*)&outp[(size_t)r * DH + (lane << 2)] =
      make_float4(x.x * v, x.y * v, x.z * v, x.w * v);
}

// ---------------- host ----------------
extern "C" void kernel_launch(void* const* d_in, const int* in_sizes, int n_in,
                              void* d_out, int out_size, void* d_ws, size_t ws_size,
                              hipStream_t stream) {
  const float* X  = (const float*)d_in[0];
  const int*   ei = (const int*)d_in[1];
  const float* W1 = (const float*)d_in[3];
  const float* b1 = (const float*)d_in[4];
  const float* a1 = (const float*)d_in[5];
  const float* W2 = (const float*)d_in[6];
  const float* b2 = (const float*)d_in[7];
  const float* a2 = (const float*)d_in[8];
  float* out = (float*)d_out;

  const int n  = in_sizes[0] / DH;
  const int E  = in_sizes[1] / 2;
  const int k1 = (4 * n + 4) / 5;
  const int k2 = (4 * k1 + 4) / 5;
  const int Pmax = E + 8 * n;
  const int* src = ei;
  const int* dst = ei + E;

  char* w = (char*)d_ws;
  size_t off = 0;
  auto alloc = [&](size_t bytes) { void* p = w + off; off += (bytes + 255) & ~(size_t)255; return p; };
  float* hA     = (float*)alloc((size_t)n * DH * 4);
  float* hB     = (float*)alloc((size_t)n * DH * 4);
  float* xp     = (float*)alloc((size_t)k1 * DH * 4);
  int*   cnt    = (int*)  alloc((size_t)n * 4);
  int*   fill   = (int*)  alloc((size_t)n * 4);   // adjacent to cnt: one memset
  int*   rowptr = (int*)  alloc((size_t)(n + 1) * 4);
  int*   eids   = (int*)  alloc((size_t)E * 4);
  int*   prow   = (int*)  alloc((size_t)n * 4);
  int*   map    = (int*)  alloc((size_t)E * 4);
  int2*  pk     = (int2*) alloc((size_t)Pmax * 8);
  int*   cnt2   = (int*)  alloc((size_t)k1 * 4);
  float* score1 = (float*)alloc((size_t)n * 4);
  float* score2 = (float*)alloc((size_t)k1 * 4);
  int*   rank1  = (int*)  alloc((size_t)n * 4);
  int*   rank2  = (int*)  alloc((size_t)k1 * 4);
  unsigned* s32 = (unsigned*)alloc((size_t)n * 4);
  int*   hist   = (int*)  alloc((size_t)NB * 4);   // hist+fill2 adjacent: one memset
  int*   fill2  = (int*)  alloc((size_t)NB * 4);
  int*   start  = (int*)  alloc((size_t)NB * 4);
  unsigned long long* mem64 = (unsigned long long*)alloc((size_t)n * 8);
  int*   bsum   = (int*)  alloc((size_t)1024 * 4);
  int2*  bsum2  = (int2*) alloc((size_t)1024 * 8);
  int*   sel1   = (int*)  alloc((size_t)k1 * 4);
  int*   sel2   = (int*)  alloc((size_t)k2 * 4);
  float* nrm1   = (float*)alloc(256);
  float* nrm2   = (float*)alloc(256);

  auto scan3 = [&](const int* in, int* outp, int m) {
    int nblk = CDIV(m, 256);
    scanA<<<nblk, 256, 0, stream>>>(in, outp, bsum, m);
    scanB<<<1, 1024, 0, stream>>>(bsum, nblk);
    scanC<<<nblk, 256, 0, stream>>>(outp, bsum, m);
  };
  auto rank_pass = [&](const unsigned* s32p, int* rank, int nL) {
    scan3(hist, start, NB);
    scatter32_kernel<<<CDIV(nL, 256), 256, 0, stream>>>(s32p, start, fill2, mem64, nL);
    rank_bucket_kernel<<<CDIV(nL, 256), 256, 0, stream>>>(s32p, start, hist, mem64, nL, rank);
  };

  // ---- CSR build ----
  hipMemsetAsync(cnt, 0, (size_t)((char*)fill - (char*)cnt) + (size_t)n * 4, stream);
  norm2_kernel<<<1, 128, 0, stream>>>(a1, a2, nrm1, nrm2);
  count_kernel<<<CDIV(E, 256), 256, 0, stream>>>(dst, cnt, E);
  {
    int nblk = CDIV(n, 256);
    scanA2<<<nblk, 256, 0, stream>>>(cnt, rowptr, prow, bsum2, n);
    scanB2<<<1, 1024, 0, stream>>>(bsum2, nblk);
    scanC2<<<nblk, 256, 0, stream>>>(rowptr, prow, bsum2, n, E);
  }
  scatter_kernel<<<CDIV(E, 256), 256, 0, stream>>>(dst, rowptr, fill, eids, E);
  sortmap_kernel<<<CDIV(n, 256), 256, 0, stream>>>(rowptr, prow, eids, map, n);
  hipMemsetAsync(pk, 0, (size_t)Pmax * 8, stream);

  // ---- level 1 ----
  gemm_128<<<CDIV(n, 32), 128, 0, stream>>>(X, W1, hA, n);
  csr_prep<<<CDIV(E, 256), 256, 0, stream>>>(eids, src, dst, map, nullptr, 0, cnt, pk, E);
  hipMemsetAsync(hist, 0, (size_t)NB * 8, stream);  // hist + fill2 (adjacent)
  conv_kernel<<<CDIV(n, 4), 256, 0, stream>>>(hA, b1, prow, cnt, pk, nullptr, cnt,
                                              a1, nrm1, hB, score1, s32, hist, n);
  rank_pass(s32, rank1, n);
  select_gather<<<CDIV(n, 8), 256, 0, stream>>>(hB, score1, rank1, k1, sel1, xp, n);

  // ---- level 2 ----
  gemm_128<<<CDIV(k1, 32), 128, 0, stream>>>(xp, W2, hA, k1);
  hipMemsetAsync(cnt2, 0, (size_t)k1 * 4, stream);
  count2_kernel<<<CDIV(E, 256), 256, 0, stream>>>(src, dst, rank1, k1, cnt2, E);
  csr_prep<<<CDIV(E, 256), 256, 0, stream>>>(eids, src, dst, map, rank1, k1, cnt2, pk, E);
  hipMemsetAsync(hist, 0, (size_t)NB * 8, stream);  // hist + fill2
  conv_kernel<<<CDIV(k1, 4), 256, 0, stream>>>(hA, b2, prow, cnt, pk, sel1, cnt2,
                                               a2, nrm2, hB, score2, s32, hist, k1);
  rank_pass(s32, rank2, k1);
  select_gather<<<CDIV(k1, 8), 256, 0, stream>>>(hB, score2, rank2, k2, sel2, out, k1);
}